// Round 1
// baseline (847.329 us; speedup 1.0000x reference)
//
#include <hip/hip_runtime.h>

#define GRID_D 64
#define NN (GRID_D * GRID_D)   // 4096 nodes per image
#define H 64
#define C_IN 12
#define B_SZ 128
#define LN_EPS 1e-5f

// ---------------------------------------------------------------------------
// Kernel 1: input projection  h[b,n,j] = sum_c x[b,c,n] * w_in[c,j] + b_in[j]
// Block = 256 threads handles one grid row (64 nodes) of one image.
// ---------------------------------------------------------------------------
__global__ __launch_bounds__(256) void k_inproj(
    const float* __restrict__ x, const float* __restrict__ w_in,
    const float* __restrict__ b_in, float* __restrict__ h)
{
    int bid = blockIdx.x;            // b*64 + r
    int b = bid >> 6, r = bid & 63;
    __shared__ float xs[C_IN][GRID_D];
    __shared__ float ws[C_IN][H];
    int tid = threadIdx.x;
    const float* xb = x + (size_t)b * C_IN * NN + (size_t)r * GRID_D;
    for (int idx = tid; idx < C_IN * GRID_D; idx += 256) {
        int c = idx >> 6, n = idx & 63;
        xs[c][n] = xb[(size_t)c * NN + n];
        ws[c][n] = w_in[idx];        // w_in is [12][64] row-major, same shape
    }
    __syncthreads();
    int j = tid & 63;
    int g = tid >> 6;                // wave id 0..3
    float bj = b_in[j];
    float* hp = h + (size_t)(b * NN + r * GRID_D) * H;
    for (int n = g * 16; n < g * 16 + 16; ++n) {
        float acc = bj;
        #pragma unroll
        for (int c = 0; c < C_IN; ++c) acc += xs[c][n] * ws[c][j];
        hp[n * H + j] = acc;         // lanes j consecutive -> coalesced
    }
}

// ---------------------------------------------------------------------------
// Kernel 2: one SAGE layer + LayerNorm + residual ReLU.
//   agg = mean over grid neighbors of h; hn = h@Ws + agg@Wn + cb;
//   h_out = h + relu(LN(hn) * lg + lb)
// Block = 256 threads handles one grid row (64 nodes) of one image.
// GEMM: 64 nodes x 64 feats, K=64 twice (self-phase, then agg-phase reusing
// the same LDS A-buffer to stay under the 64KB static LDS cap).
// Thread tile: 4 nodes x 4 features.
// ---------------------------------------------------------------------------
__global__ __launch_bounds__(256) void k_layer(
    const float* __restrict__ h_in, float* __restrict__ h_out,
    const float* __restrict__ Ws, const float* __restrict__ Wn,
    const float* __restrict__ cb, const float* __restrict__ lg,
    const float* __restrict__ lb)
{
    int bid = blockIdx.x;
    int b = bid >> 6, r = bid & 63;
    __shared__ float sw[2 * H][H];   // [k][j], rows 0..63 = Ws, 64..127 = Wn (32KB)
    __shared__ float sa[H][68];      // [feat k][node n], stride 68 for 16B-aligned
                                     // float4 reads + reduced write bank conflicts
    int tid = threadIdx.x;
    for (int idx = tid; idx < H * H; idx += 256) {
        sw[idx >> 6][idx & 63]     = Ws[idx];
        sw[(idx >> 6) + H][idx & 63] = Wn[idx];
    }
    const float* hb = h_in + (size_t)b * NN * H;
    int nodebase = r * GRID_D;
    int j = tid & 63, g = tid >> 6;
    float aggr[16];                  // agg values stashed in regs for phase 2
    #pragma unroll
    for (int it = 0; it < 16; ++it) {
        int n = g + 4 * it;          // column within this grid row
        int bn = nodebase + n;
        float self = hb[(size_t)bn * H + j];
        float acc = 0.f, deg = 0.f;
        if (n > 0)  { acc += hb[(size_t)(bn - 1)      * H + j]; deg += 1.f; }
        if (n < 63) { acc += hb[(size_t)(bn + 1)      * H + j]; deg += 1.f; }
        if (r > 0)  { acc += hb[(size_t)(bn - GRID_D) * H + j]; deg += 1.f; }
        if (r < 63) { acc += hb[(size_t)(bn + GRID_D) * H + j]; deg += 1.f; }
        sa[j][n] = self;
        aggr[it] = acc * (1.0f / deg);
    }
    __syncthreads();

    int tx = tid & 15, ty = tid >> 4;
    int n0 = ty * 4, j0 = tx * 4;
    float acc[4][4] = {};

    // Phase 1: self contribution, K = 0..63 with Ws
    #pragma unroll 4
    for (int k = 0; k < H; ++k) {
        float4 a4 = *(const float4*)&sa[k][n0];
        float4 w4 = *(const float4*)&sw[k][j0];
        float av[4] = {a4.x, a4.y, a4.z, a4.w};
        float wv[4] = {w4.x, w4.y, w4.z, w4.w};
        #pragma unroll
        for (int i = 0; i < 4; ++i)
            #pragma unroll
            for (int jj = 0; jj < 4; ++jj)
                acc[i][jj] += av[i] * wv[jj];
    }
    __syncthreads();                 // phase-1 reads done before overwrite
    #pragma unroll
    for (int it = 0; it < 16; ++it) {
        int n = g + 4 * it;
        sa[j][n] = aggr[it];
    }
    __syncthreads();
    // Phase 2: aggregate contribution with Wn
    #pragma unroll 4
    for (int k = 0; k < H; ++k) {
        float4 a4 = *(const float4*)&sa[k][n0];
        float4 w4 = *(const float4*)&sw[k + H][j0];
        float av[4] = {a4.x, a4.y, a4.z, a4.w};
        float wv[4] = {w4.x, w4.y, w4.z, w4.w};
        #pragma unroll
        for (int i = 0; i < 4; ++i)
            #pragma unroll
            for (int jj = 0; jj < 4; ++jj)
                acc[i][jj] += av[i] * wv[jj];
    }

    // Epilogue: +bias, LayerNorm over 64 feats (16 lanes x 4 feats each),
    // residual + ReLU, store.
    float cbv[4], lgv[4], lbv[4];
    #pragma unroll
    for (int jj = 0; jj < 4; ++jj) {
        cbv[jj] = cb[j0 + jj]; lgv[jj] = lg[j0 + jj]; lbv[jj] = lb[j0 + jj];
    }
    const float* hrow = h_in + (size_t)(b * NN + nodebase) * H;
    float* orow       = h_out + (size_t)(b * NN + nodebase) * H;
    #pragma unroll
    for (int i = 0; i < 4; ++i) {
        int n = n0 + i;
        float v[4]; float s1 = 0.f, s2 = 0.f;
        #pragma unroll
        for (int jj = 0; jj < 4; ++jj) {
            float t = acc[i][jj] + cbv[jj];
            v[jj] = t; s1 += t; s2 += t * t;
        }
        // reduce across the 16 lanes sharing this node (xor masks stay in-group)
        #pragma unroll
        for (int m = 1; m < 16; m <<= 1) {
            s1 += __shfl_xor(s1, m);
            s2 += __shfl_xor(s2, m);
        }
        float mu   = s1 * (1.0f / H);
        float var  = s2 * (1.0f / H) - mu * mu;
        float rstd = rsqrtf(var + LN_EPS);
        float4 self4 = *(const float4*)&hrow[(size_t)n * H + j0];
        float sv[4] = {self4.x, self4.y, self4.z, self4.w};
        float o[4];
        #pragma unroll
        for (int jj = 0; jj < 4; ++jj) {
            float t = (v[jj] - mu) * rstd * lgv[jj] + lbv[jj];
            o[jj] = sv[jj] + fmaxf(t, 0.f);
        }
        *(float4*)&orow[(size_t)n * H + j0] = make_float4(o[0], o[1], o[2], o[3]);
    }
}

// ---------------------------------------------------------------------------
// Kernel 3: head  logit[bn] = sum_j h[bn,j]*w_head[j] + b_head
// One wave per 64 nodes (sequential), full-wave shuffle reduction.
// ---------------------------------------------------------------------------
__global__ __launch_bounds__(256) void k_head(
    const float* __restrict__ h, const float* __restrict__ w_head,
    const float* __restrict__ b_head, float* __restrict__ out)
{
    int tid = threadIdx.x;
    int wave = tid >> 6, lane = tid & 63;
    int nodebase = (blockIdx.x * 4 + wave) * 64;
    float wj = w_head[lane];
    float bh = b_head[0];
    for (int n = nodebase; n < nodebase + 64; ++n) {
        float v = h[(size_t)n * H + lane] * wj;
        #pragma unroll
        for (int m = 32; m >= 1; m >>= 1) v += __shfl_xor(v, m);
        if (lane == 0) out[n] = v + bh;
    }
}

// ---------------------------------------------------------------------------
extern "C" void kernel_launch(void* const* d_in, const int* in_sizes, int n_in,
                              void* d_out, int out_size, void* d_ws, size_t ws_size,
                              hipStream_t stream) {
    const float* x      = (const float*)d_in[0];
    // d_in[1] edge_index: fixed grid 4-neighborhood -> computed as stencil, unused
    const float* w_in   = (const float*)d_in[2];
    const float* b_in   = (const float*)d_in[3];
    const float* w_self = (const float*)d_in[4];
    const float* w_neigh= (const float*)d_in[5];
    const float* conv_b = (const float*)d_in[6];
    const float* ln_g   = (const float*)d_in[7];
    const float* ln_b   = (const float*)d_in[8];
    const float* w_head = (const float*)d_in[9];
    const float* b_head = (const float*)d_in[10];
    float* out = (float*)d_out;

    // ping-pong h buffers: 2 x 128*4096*64 fp32 = 268 MB of workspace
    float* h_a = (float*)d_ws;
    float* h_b = h_a + (size_t)B_SZ * NN * H;

    dim3 blk(256);
    k_inproj<<<B_SZ * GRID_D, blk, 0, stream>>>(x, w_in, b_in, h_a);
    const float* hi = h_a;
    float* ho = h_b;
    for (int l = 0; l < 3; ++l) {
        k_layer<<<B_SZ * GRID_D, blk, 0, stream>>>(
            hi, ho, w_self + (size_t)l * H * H, w_neigh + (size_t)l * H * H,
            conv_b + l * H, ln_g + l * H, ln_b + l * H);
        const float* t = hi; hi = ho; ho = (float*)t;
    }
    k_head<<<(B_SZ * NN) / 256, blk, 0, stream>>>(hi, w_head, b_head, out);
}

// Round 2
// 383.216 us; speedup vs baseline: 2.2111x; 2.2111x over previous
//
#include <hip/hip_runtime.h>

#define GRID_D 64
#define NN (GRID_D * GRID_D)   // 4096 nodes per image
#define H 64
#define C_IN 12
#define B_SZ 128
#define LN_EPS 1e-5f
#define LDK 72                 // padded K stride (bf16 elems) for LDS tiles

typedef __bf16 bf16x8 __attribute__((ext_vector_type(8)));
typedef __bf16 bf16x4 __attribute__((ext_vector_type(4)));
typedef float  f32x4  __attribute__((ext_vector_type(4)));

// ---------------------------------------------------------------------------
// Kernel 1: input projection  h[b,n,j] = sum_c x[b,c,n] * w_in[c,j] + b_in[j]
// ---------------------------------------------------------------------------
__global__ __launch_bounds__(256) void k_inproj(
    const float* __restrict__ x, const float* __restrict__ w_in,
    const float* __restrict__ b_in, float* __restrict__ h)
{
    int bid = blockIdx.x;            // b*64 + r
    int b = bid >> 6, r = bid & 63;
    __shared__ float xs[C_IN][GRID_D];
    __shared__ float ws[C_IN][H];
    int tid = threadIdx.x;
    const float* xb = x + (size_t)b * C_IN * NN + (size_t)r * GRID_D;
    for (int idx = tid; idx < C_IN * GRID_D; idx += 256) {
        int c = idx >> 6, n = idx & 63;
        xs[c][n] = xb[(size_t)c * NN + n];
        ws[c][n] = w_in[idx];        // w_in is [12][64] row-major
    }
    __syncthreads();
    int j = tid & 63;
    int g = tid >> 6;
    float bj = b_in[j];
    float* hp = h + (size_t)(b * NN + r * GRID_D) * H;
    for (int n = g * 16; n < g * 16 + 16; ++n) {
        float acc = bj;
        #pragma unroll
        for (int c = 0; c < C_IN; ++c) acc += xs[c][n] * ws[c][j];
        hp[n * H + j] = acc;
    }
}

// ---------------------------------------------------------------------------
// Kernel 2: one SAGE layer + LayerNorm + residual ReLU, MFMA version.
// Block = 256 threads (4 waves) handles 2 grid rows (128 nodes) of one image.
// GEMM C[128n][64j] = selfbf[128][64] @ Ws  +  aggbf[128][64] @ Wn  via
// mfma_f32_16x16x32_bf16; A-tiles staged bf16 in LDS (phase-shared buffer),
// weights staged transposed bf16. h state stays fp32 in global (residual
// precision); stencil agg reads neighbors from global (L1/L2-served).
// ---------------------------------------------------------------------------
__global__ __launch_bounds__(256) void k_layer(
    const float* __restrict__ h_in, float* __restrict__ h_out,
    const float* __restrict__ Ws, const float* __restrict__ Wn,
    const float* __restrict__ cb, const float* __restrict__ lg,
    const float* __restrict__ lb)
{
    __shared__ __bf16 sa[128][LDK];      // A-tile: self (phase 1) then agg (phase 2)
    __shared__ __bf16 wt[2][H][LDK];     // wt[g][j][k] = W_g[k][j]  (transposed)

    int tid = threadIdx.x;
    int bid = blockIdx.x;                // img*32 + rowpair
    int img = bid >> 5, rp = bid & 31;
    int r0 = rp * 2;
    const float* hb = h_in + (size_t)img * NN * H;
    float*       ho = h_out + (size_t)img * NN * H;
    int nb = r0 * GRID_D;                // first local node of this block

    // ---- stage weights transposed (bf16) ----
    for (int idx = tid; idx < H * H; idx += 256) {
        int k = idx >> 6, j = idx & 63;
        wt[0][j][k] = (__bf16)Ws[idx];
        wt[1][j][k] = (__bf16)Wn[idx];
    }

    // ---- stencil phase: 128 nodes x 16 float4-cols = 2048 items, 8/thread ----
    float agg[8][4];
    #pragma unroll
    for (int gi = 0; gi < 8; ++gi) {
        int q = gi * 256 + tid;
        int n = q >> 4;                  // local node 0..127
        int f4 = q & 15;                 // float4 column
        int col = n & 63;                // grid column
        int row = r0 + (n >> 6);         // grid row
        const float* p = hb + (size_t)(nb + n) * H + f4 * 4;
        float4 s = *(const float4*)p;
        float a0 = 0.f, a1 = 0.f, a2 = 0.f, a3 = 0.f, deg = 0.f;
        if (col > 0)  { float4 v = *(const float4*)(p - H);          a0+=v.x; a1+=v.y; a2+=v.z; a3+=v.w; deg+=1.f; }
        if (col < 63) { float4 v = *(const float4*)(p + H);          a0+=v.x; a1+=v.y; a2+=v.z; a3+=v.w; deg+=1.f; }
        if (row > 0)  { float4 v = *(const float4*)(p - GRID_D * H); a0+=v.x; a1+=v.y; a2+=v.z; a3+=v.w; deg+=1.f; }
        if (row < 63) { float4 v = *(const float4*)(p + GRID_D * H); a0+=v.x; a1+=v.y; a2+=v.z; a3+=v.w; deg+=1.f; }
        float inv = (deg == 2.f) ? 0.5f : (deg == 3.f ? (1.f / 3.f) : 0.25f);
        agg[gi][0] = a0 * inv; agg[gi][1] = a1 * inv;
        agg[gi][2] = a2 * inv; agg[gi][3] = a3 * inv;
        bf16x4 sv = { (__bf16)s.x, (__bf16)s.y, (__bf16)s.z, (__bf16)s.w };
        *(bf16x4*)&sa[n][f4 * 4] = sv;
    }
    __syncthreads();

    // ---- GEMM setup ----
    int wv = tid >> 6, ln = tid & 63;
    int lrow = ln & 15;                  // fragment dim index (A row / B col / C col)
    int kgrp = ln >> 4;                  // k-group (8 elems each)
    int wnode = wv * 32;                 // wave's local node base
    f32x4 acc[2][4];                     // [node-tile][feat-tile]
    #pragma unroll
    for (int nt = 0; nt < 2; ++nt)
        #pragma unroll
        for (int ft = 0; ft < 4; ++ft) acc[nt][ft] = (f32x4){0.f, 0.f, 0.f, 0.f};

    // ---- phase 1: self @ Ws ----
    #pragma unroll
    for (int ks = 0; ks < 2; ++ks) {
        int k0 = ks * 32 + kgrp * 8;
        bf16x8 a0 = *(bf16x8*)&sa[wnode + lrow][k0];
        bf16x8 a1 = *(bf16x8*)&sa[wnode + 16 + lrow][k0];
        #pragma unroll
        for (int ft = 0; ft < 4; ++ft) {
            bf16x8 bfrag = *(bf16x8*)&wt[0][ft * 16 + lrow][k0];
            acc[0][ft] = __builtin_amdgcn_mfma_f32_16x16x32_bf16(a0, bfrag, acc[0][ft], 0, 0, 0);
            acc[1][ft] = __builtin_amdgcn_mfma_f32_16x16x32_bf16(a1, bfrag, acc[1][ft], 0, 0, 0);
        }
    }
    __syncthreads();                     // phase-1 reads done before overwrite

    // ---- swap A-buffer to agg ----
    #pragma unroll
    for (int gi = 0; gi < 8; ++gi) {
        int q = gi * 256 + tid;
        int n = q >> 4;
        int f4 = q & 15;
        bf16x4 av = { (__bf16)agg[gi][0], (__bf16)agg[gi][1],
                      (__bf16)agg[gi][2], (__bf16)agg[gi][3] };
        *(bf16x4*)&sa[n][f4 * 4] = av;
    }
    __syncthreads();

    // ---- phase 2: agg @ Wn ----
    #pragma unroll
    for (int ks = 0; ks < 2; ++ks) {
        int k0 = ks * 32 + kgrp * 8;
        bf16x8 a0 = *(bf16x8*)&sa[wnode + lrow][k0];
        bf16x8 a1 = *(bf16x8*)&sa[wnode + 16 + lrow][k0];
        #pragma unroll
        for (int ft = 0; ft < 4; ++ft) {
            bf16x8 bfrag = *(bf16x8*)&wt[1][ft * 16 + lrow][k0];
            acc[0][ft] = __builtin_amdgcn_mfma_f32_16x16x32_bf16(a0, bfrag, acc[0][ft], 0, 0, 0);
            acc[1][ft] = __builtin_amdgcn_mfma_f32_16x16x32_bf16(a1, bfrag, acc[1][ft], 0, 0, 0);
        }
    }

    // ---- epilogue: +bias, LN over 64 feats, residual + ReLU, store fp32 ----
    float cbv[4], lgv[4], lbv[4];
    #pragma unroll
    for (int ft = 0; ft < 4; ++ft) {
        int j = ft * 16 + lrow;
        cbv[ft] = cb[j]; lgv[ft] = lg[j]; lbv[ft] = lb[j];
    }
    #pragma unroll
    for (int nt = 0; nt < 2; ++nt) {
        #pragma unroll
        for (int t = 0; t < 4; ++t) {
            int nl = wnode + nt * 16 + 4 * kgrp + t;   // local node for this C-row
            size_t base = (size_t)(nb + nl) * H;
            float v[4], s1 = 0.f, s2 = 0.f;
            #pragma unroll
            for (int ft = 0; ft < 4; ++ft) {
                float xv = acc[nt][ft][t] + cbv[ft];
                v[ft] = xv; s1 += xv; s2 += xv * xv;
            }
            #pragma unroll
            for (int m = 1; m < 16; m <<= 1) {
                s1 += __shfl_xor(s1, m);
                s2 += __shfl_xor(s2, m);
            }
            float mu   = s1 * (1.0f / H);
            float var  = s2 * (1.0f / H) - mu * mu;
            float rstd = rsqrtf(var + LN_EPS);
            #pragma unroll
            for (int ft = 0; ft < 4; ++ft) {
                int j = ft * 16 + lrow;
                float sv = hb[base + j];               // residual (L2-hit re-read)
                float o  = sv + fmaxf((v[ft] - mu) * rstd * lgv[ft] + lbv[ft], 0.f);
                ho[base + j] = o;
            }
        }
    }
}

// ---------------------------------------------------------------------------
// Kernel 3: head  logit[bn] = sum_j h[bn,j]*w_head[j] + b_head
// ---------------------------------------------------------------------------
__global__ __launch_bounds__(256) void k_head(
    const float* __restrict__ h, const float* __restrict__ w_head,
    const float* __restrict__ b_head, float* __restrict__ out)
{
    int tid = threadIdx.x;
    int wave = tid >> 6, lane = tid & 63;
    int nodebase = (blockIdx.x * 4 + wave) * 64;
    float wj = w_head[lane];
    float bh = b_head[0];
    for (int n = nodebase; n < nodebase + 64; ++n) {
        float v = h[(size_t)n * H + lane] * wj;
        #pragma unroll
        for (int m = 32; m >= 1; m >>= 1) v += __shfl_xor(v, m);
        if (lane == 0) out[n] = v + bh;
    }
}

// ---------------------------------------------------------------------------
extern "C" void kernel_launch(void* const* d_in, const int* in_sizes, int n_in,
                              void* d_out, int out_size, void* d_ws, size_t ws_size,
                              hipStream_t stream) {
    const float* x      = (const float*)d_in[0];
    // d_in[1] edge_index: fixed grid 4-neighborhood -> computed as stencil, unused
    const float* w_in   = (const float*)d_in[2];
    const float* b_in   = (const float*)d_in[3];
    const float* w_self = (const float*)d_in[4];
    const float* w_neigh= (const float*)d_in[5];
    const float* conv_b = (const float*)d_in[6];
    const float* ln_g   = (const float*)d_in[7];
    const float* ln_b   = (const float*)d_in[8];
    const float* w_head = (const float*)d_in[9];
    const float* b_head = (const float*)d_in[10];
    float* out = (float*)d_out;

    float* h_a = (float*)d_ws;
    float* h_b = h_a + (size_t)B_SZ * NN * H;

    dim3 blk(256);
    k_inproj<<<B_SZ * GRID_D, blk, 0, stream>>>(x, w_in, b_in, h_a);
    const float* hi = h_a;
    float* ho = h_b;
    for (int l = 0; l < 3; ++l) {
        k_layer<<<B_SZ * 32, blk, 0, stream>>>(
            hi, ho, w_self + (size_t)l * H * H, w_neigh + (size_t)l * H * H,
            conv_b + l * H, ln_g + l * H, ln_b + l * H);
        const float* t = hi; hi = ho; ho = (float*)t;
    }
    k_head<<<(B_SZ * NN) / 256, blk, 0, stream>>>(hi, w_head, b_head, out);
}

// Round 3
// 191.735 us; speedup vs baseline: 4.4193x; 1.9987x over previous
//
#include <hip/hip_runtime.h>

#define GRID_D 64
#define NN (GRID_D * GRID_D)   // 4096 nodes per image
#define H 64
#define C_IN 12
#define B_SZ 128
#define LN_EPS 1e-5f
#define LDK 72                 // padded K stride (bf16 elems) for LDS tiles

typedef __bf16 bf16x8 __attribute__((ext_vector_type(8)));
typedef __bf16 bf16x4 __attribute__((ext_vector_type(4)));
typedef float  f32x4  __attribute__((ext_vector_type(4)));

// ---------------------------------------------------------------------------
// Kernel 1: input projection  h[b,n,j] = sum_c x[b,c,n] * w_in[c,j] + b_in[j]
// Output bf16 (h state is bf16 everywhere; 134MB ping-pong set fits L3).
// ---------------------------------------------------------------------------
__global__ __launch_bounds__(256) void k_inproj(
    const float* __restrict__ x, const float* __restrict__ w_in,
    const float* __restrict__ b_in, __bf16* __restrict__ h)
{
    int bid = blockIdx.x;            // b*64 + r
    int b = bid >> 6, r = bid & 63;
    __shared__ float xs[C_IN][GRID_D];
    __shared__ float ws[C_IN][H];
    int tid = threadIdx.x;
    const float* xb = x + (size_t)b * C_IN * NN + (size_t)r * GRID_D;
    for (int idx = tid; idx < C_IN * GRID_D; idx += 256) {
        int c = idx >> 6, n = idx & 63;
        xs[c][n] = xb[(size_t)c * NN + n];
        ws[c][n] = w_in[idx];        // w_in is [12][64] row-major
    }
    __syncthreads();
    int j = tid & 63;
    int g = tid >> 6;
    float bj = b_in[j];
    __bf16* hp = h + (size_t)(b * NN + r * GRID_D) * H;
    for (int n = g * 16; n < g * 16 + 16; ++n) {
        float acc = bj;
        #pragma unroll
        for (int c = 0; c < C_IN; ++c) acc += xs[c][n] * ws[c][j];
        hp[n * H + j] = (__bf16)acc;
    }
}

// ---------------------------------------------------------------------------
// Kernel 2: one SAGE layer + LayerNorm + residual ReLU (MFMA, bf16 h state).
// Block = 256 threads (4 waves) handles 2 grid rows (128 nodes) of one image.
// LAST=true fuses the head: writes fp32 logits instead of h.
// ---------------------------------------------------------------------------
template <bool LAST>
__global__ __launch_bounds__(256) void k_layer(
    const __bf16* __restrict__ h_in, __bf16* __restrict__ h_out,
    float* __restrict__ logits,
    const float* __restrict__ Ws, const float* __restrict__ Wn,
    const float* __restrict__ cb, const float* __restrict__ lg,
    const float* __restrict__ lb,
    const float* __restrict__ w_head, const float* __restrict__ b_head)
{
    __shared__ __bf16 sa[128][LDK];      // A-tile: self (phase 1) then agg (phase 2)
    __shared__ __bf16 wt[2][H][LDK];     // wt[g][j][k] = W_g[k][j]  (transposed)

    int tid = threadIdx.x;
    int bid = blockIdx.x;                // img*32 + rowpair
    int img = bid >> 5, rp = bid & 31;
    int r0 = rp * 2;
    const __bf16* hb = h_in + (size_t)img * NN * H;
    __bf16*       ho = h_out + (size_t)img * NN * H;
    int nb = r0 * GRID_D;                // first local node of this block

    // ---- stage weights transposed (bf16) ----
    for (int idx = tid; idx < H * H; idx += 256) {
        int k = idx >> 6, j = idx & 63;
        wt[0][j][k] = (__bf16)Ws[idx];
        wt[1][j][k] = (__bf16)Wn[idx];
    }

    // ---- stencil phase: 128 nodes x 8 bf16x8-groups = 1024 items, 4/thread ----
    bf16x8 aggv[4];
    #pragma unroll
    for (int gi = 0; gi < 4; ++gi) {
        int q = gi * 256 + tid;
        int n = q >> 3;                  // local node 0..127
        int c8 = q & 7;                  // 8-feat group
        int col = n & 63;                // grid column
        int row = r0 + (n >> 6);         // grid row
        const __bf16* p = hb + (size_t)(nb + n) * H + c8 * 8;
        bf16x8 s = *(const bf16x8*)p;
        float a[8] = {0.f, 0.f, 0.f, 0.f, 0.f, 0.f, 0.f, 0.f};
        float deg = 0.f;
        if (col > 0)  { bf16x8 v = *(const bf16x8*)(p - H);
            #pragma unroll
            for (int e = 0; e < 8; ++e) a[e] += (float)v[e]; deg += 1.f; }
        if (col < 63) { bf16x8 v = *(const bf16x8*)(p + H);
            #pragma unroll
            for (int e = 0; e < 8; ++e) a[e] += (float)v[e]; deg += 1.f; }
        if (row > 0)  { bf16x8 v = *(const bf16x8*)(p - GRID_D * H);
            #pragma unroll
            for (int e = 0; e < 8; ++e) a[e] += (float)v[e]; deg += 1.f; }
        if (row < 63) { bf16x8 v = *(const bf16x8*)(p + GRID_D * H);
            #pragma unroll
            for (int e = 0; e < 8; ++e) a[e] += (float)v[e]; deg += 1.f; }
        float inv = (deg == 2.f) ? 0.5f : (deg == 3.f ? (1.f / 3.f) : 0.25f);
        bf16x8 av;
        #pragma unroll
        for (int e = 0; e < 8; ++e) av[e] = (__bf16)(a[e] * inv);
        aggv[gi] = av;
        *(bf16x8*)&sa[n][c8 * 8] = s;    // self is already bf16 — store as-is
    }
    __syncthreads();

    // ---- GEMM setup ----
    int wv = tid >> 6, ln = tid & 63;
    int lrow = ln & 15;                  // fragment dim index (A row / B col / C col)
    int kgrp = ln >> 4;                  // k-group (8 elems each)
    int wnode = wv * 32;                 // wave's local node base
    f32x4 acc[2][4];                     // [node-tile][feat-tile]
    #pragma unroll
    for (int nt = 0; nt < 2; ++nt)
        #pragma unroll
        for (int ft = 0; ft < 4; ++ft) acc[nt][ft] = (f32x4){0.f, 0.f, 0.f, 0.f};

    // ---- phase 1: self @ Ws ----
    #pragma unroll
    for (int ks = 0; ks < 2; ++ks) {
        int k0 = ks * 32 + kgrp * 8;
        bf16x8 a0 = *(bf16x8*)&sa[wnode + lrow][k0];
        bf16x8 a1 = *(bf16x8*)&sa[wnode + 16 + lrow][k0];
        #pragma unroll
        for (int ft = 0; ft < 4; ++ft) {
            bf16x8 bfrag = *(bf16x8*)&wt[0][ft * 16 + lrow][k0];
            acc[0][ft] = __builtin_amdgcn_mfma_f32_16x16x32_bf16(a0, bfrag, acc[0][ft], 0, 0, 0);
            acc[1][ft] = __builtin_amdgcn_mfma_f32_16x16x32_bf16(a1, bfrag, acc[1][ft], 0, 0, 0);
        }
    }
    __syncthreads();                     // phase-1 reads done before overwrite

    // ---- swap A-buffer to agg ----
    #pragma unroll
    for (int gi = 0; gi < 4; ++gi) {
        int q = gi * 256 + tid;
        int n = q >> 3;
        int c8 = q & 7;
        *(bf16x8*)&sa[n][c8 * 8] = aggv[gi];
    }
    __syncthreads();

    // ---- phase 2: agg @ Wn ----
    #pragma unroll
    for (int ks = 0; ks < 2; ++ks) {
        int k0 = ks * 32 + kgrp * 8;
        bf16x8 a0 = *(bf16x8*)&sa[wnode + lrow][k0];
        bf16x8 a1 = *(bf16x8*)&sa[wnode + 16 + lrow][k0];
        #pragma unroll
        for (int ft = 0; ft < 4; ++ft) {
            bf16x8 bfrag = *(bf16x8*)&wt[1][ft * 16 + lrow][k0];
            acc[0][ft] = __builtin_amdgcn_mfma_f32_16x16x32_bf16(a0, bfrag, acc[0][ft], 0, 0, 0);
            acc[1][ft] = __builtin_amdgcn_mfma_f32_16x16x32_bf16(a1, bfrag, acc[1][ft], 0, 0, 0);
        }
    }

    // ---- epilogue: +bias, LN over 64 feats, residual + ReLU ----
    float cbv[4], lgv[4], lbv[4], whv[4];
    #pragma unroll
    for (int ft = 0; ft < 4; ++ft) {
        int j = ft * 16 + lrow;
        cbv[ft] = cb[j]; lgv[ft] = lg[j]; lbv[ft] = lb[j];
        if (LAST) whv[ft] = w_head[j];
    }
    float bh = LAST ? b_head[0] : 0.f;
    #pragma unroll
    for (int nt = 0; nt < 2; ++nt) {
        #pragma unroll
        for (int t = 0; t < 4; ++t) {
            int nl = wnode + nt * 16 + 4 * kgrp + t;   // local node for this C-row
            size_t base = (size_t)(nb + nl) * H;
            float v[4], s1 = 0.f, s2 = 0.f;
            #pragma unroll
            for (int ft = 0; ft < 4; ++ft) {
                float xv = acc[nt][ft][t] + cbv[ft];
                v[ft] = xv; s1 += xv; s2 += xv * xv;
            }
            #pragma unroll
            for (int m = 1; m < 16; m <<= 1) {
                s1 += __shfl_xor(s1, m);
                s2 += __shfl_xor(s2, m);
            }
            float mu   = s1 * (1.0f / H);
            float var  = s2 * (1.0f / H) - mu * mu;
            float rstd = rsqrtf(var + LN_EPS);
            if (LAST) {
                float part = 0.f;
                #pragma unroll
                for (int ft = 0; ft < 4; ++ft) {
                    int j = ft * 16 + lrow;
                    float sv = (float)hb[base + j];
                    float o  = sv + fmaxf((v[ft] - mu) * rstd * lgv[ft] + lbv[ft], 0.f);
                    part += o * whv[ft];
                }
                #pragma unroll
                for (int m = 1; m < 16; m <<= 1) part += __shfl_xor(part, m);
                if (lrow == 0) logits[(size_t)img * NN + nb + nl] = part + bh;
            } else {
                #pragma unroll
                for (int ft = 0; ft < 4; ++ft) {
                    int j = ft * 16 + lrow;
                    float sv = (float)hb[base + j];
                    float o  = sv + fmaxf((v[ft] - mu) * rstd * lgv[ft] + lbv[ft], 0.f);
                    ho[base + j] = (__bf16)o;
                }
            }
        }
    }
}

// ---------------------------------------------------------------------------
extern "C" void kernel_launch(void* const* d_in, const int* in_sizes, int n_in,
                              void* d_out, int out_size, void* d_ws, size_t ws_size,
                              hipStream_t stream) {
    const float* x      = (const float*)d_in[0];
    // d_in[1] edge_index: fixed grid 4-neighborhood -> computed as stencil, unused
    const float* w_in   = (const float*)d_in[2];
    const float* b_in   = (const float*)d_in[3];
    const float* w_self = (const float*)d_in[4];
    const float* w_neigh= (const float*)d_in[5];
    const float* conv_b = (const float*)d_in[6];
    const float* ln_g   = (const float*)d_in[7];
    const float* ln_b   = (const float*)d_in[8];
    const float* w_head = (const float*)d_in[9];
    const float* b_head = (const float*)d_in[10];
    float* out = (float*)d_out;

    __bf16* h_a = (__bf16*)d_ws;
    __bf16* h_b = h_a + (size_t)B_SZ * NN * H;

    dim3 blk(256);
    k_inproj<<<B_SZ * GRID_D, blk, 0, stream>>>(x, w_in, b_in, h_a);
    k_layer<false><<<B_SZ * 32, blk, 0, stream>>>(
        h_a, h_b, out, w_self, w_neigh, conv_b, ln_g, ln_b, w_head, b_head);
    k_layer<false><<<B_SZ * 32, blk, 0, stream>>>(
        h_b, h_a, out, w_self + H * H, w_neigh + H * H,
        conv_b + H, ln_g + H, ln_b + H, w_head, b_head);
    k_layer<true><<<B_SZ * 32, blk, 0, stream>>>(
        h_a, h_b, out, w_self + 2 * H * H, w_neigh + 2 * H * H,
        conv_b + 2 * H, ln_g + 2 * H, ln_b + 2 * H, w_head, b_head);
}

// Round 4
// 164.838 us; speedup vs baseline: 5.1404x; 1.1632x over previous
//
#include <hip/hip_runtime.h>

#define GRID_D 64
#define NN (GRID_D * GRID_D)   // 4096 nodes per image
#define H 64
#define C_IN 12
#define B_SZ 128
#define LN_EPS 1e-5f

#define LDK 72                     // padded feat stride (bf16 elems), 144B (16B-aligned)
#define ST_ROW_STRIDE (66 * LDK)   // st row stride in elems (66 cols incl. borders)
#define ST_ELEMS (6 * 66 * LDK)    // h tile: 6 rows x 66 cols x 72
#define WT_ELEMS (2 * 64 * LDK)    // transposed weights
#define SMEM_BYTES ((ST_ELEMS + WT_ELEMS) * 2)   // 75,456 B

typedef __bf16 bf16x8 __attribute__((ext_vector_type(8)));
typedef float  f32x4  __attribute__((ext_vector_type(4)));

__device__ __forceinline__ float b2f_lo(unsigned u) {
    union { unsigned x; float f; } c; c.x = u << 16; return c.f;
}
__device__ __forceinline__ float b2f_hi(unsigned u) {
    union { unsigned x; float f; } c; c.x = u & 0xffff0000u; return c.f;
}

// Build the agg A-fragment in registers: mean of 4 neighbors from the LDS tile.
__device__ __forceinline__ bf16x8 agg_frag(
    const __bf16* Lp, const __bf16* Rp, const __bf16* Up, const __bf16* Dp, float inv)
{
    uint4 l = *(const uint4*)Lp, r = *(const uint4*)Rp;
    uint4 u = *(const uint4*)Up, d = *(const uint4*)Dp;
    const unsigned* lw = (const unsigned*)&l;
    const unsigned* rw = (const unsigned*)&r;
    const unsigned* uw = (const unsigned*)&u;
    const unsigned* dw = (const unsigned*)&d;
    bf16x8 o;
    #pragma unroll
    for (int w = 0; w < 4; ++w) {
        float lo = (b2f_lo(lw[w]) + b2f_lo(rw[w]) + b2f_lo(uw[w]) + b2f_lo(dw[w])) * inv;
        float hi = (b2f_hi(lw[w]) + b2f_hi(rw[w]) + b2f_hi(uw[w]) + b2f_hi(dw[w])) * inv;
        o[2 * w]     = (__bf16)lo;
        o[2 * w + 1] = (__bf16)hi;
    }
    return o;
}

// ---------------------------------------------------------------------------
// Kernel 1: input projection  h[b,n,j] = sum_c x[b,c,n] * w_in[c,j] + b_in[j]
// ---------------------------------------------------------------------------
__global__ __launch_bounds__(256) void k_inproj(
    const float* __restrict__ x, const float* __restrict__ w_in,
    const float* __restrict__ b_in, __bf16* __restrict__ h)
{
    int bid = blockIdx.x;            // b*64 + r
    int b = bid >> 6, r = bid & 63;
    __shared__ float xs[C_IN][GRID_D];
    __shared__ float ws[C_IN][H];
    int tid = threadIdx.x;
    const float* xb = x + (size_t)b * C_IN * NN + (size_t)r * GRID_D;
    for (int idx = tid; idx < C_IN * GRID_D; idx += 256) {
        int c = idx >> 6, n = idx & 63;
        xs[c][n] = xb[(size_t)c * NN + n];
        ws[c][n] = w_in[idx];
    }
    __syncthreads();
    int j = tid & 63;
    int g = tid >> 6;
    float bj = b_in[j];
    __bf16* hp = h + (size_t)(b * NN + r * GRID_D) * H;
    for (int n = g * 16; n < g * 16 + 16; ++n) {
        float acc = bj;
        #pragma unroll
        for (int c = 0; c < C_IN; ++c) acc += xs[c][n] * ws[c][j];
        hp[n * H + j] = (__bf16)acc;
    }
}

// ---------------------------------------------------------------------------
// Kernel 2: one SAGE layer + LayerNorm + residual ReLU.
// Block = 512 threads (8 waves) handles 4 grid rows (256 nodes) of one image.
// h tile (4 rows + 1 halo row each side, zero-padded cols) staged to LDS once;
// self A-frags read from tile; agg A-frags built on-the-fly in registers;
// residual from LDS. Single __syncthreads. LAST fuses the head.
// ---------------------------------------------------------------------------
template <bool LAST>
__global__ __launch_bounds__(512, 4) void k_layer(
    const __bf16* __restrict__ h_in, __bf16* __restrict__ h_out,
    float* __restrict__ logits,
    const float* __restrict__ Ws, const float* __restrict__ Wn,
    const float* __restrict__ cb, const float* __restrict__ lg,
    const float* __restrict__ lb,
    const float* __restrict__ w_head, const float* __restrict__ b_head)
{
    extern __shared__ __bf16 smem[];
    __bf16* st = smem;                 // [6 rows][66 cols][LDK]
    __bf16* wt = smem + ST_ELEMS;      // [2][64 j][LDK]  wt[g][j][k] = W_g[k][j]

    int tid = threadIdx.x;
    int bid = blockIdx.x;              // img*16 + tile
    int img = bid >> 4, tile = bid & 15;
    int r0 = tile * 4;
    const __bf16* hb = h_in + (size_t)img * NN * H;
    __bf16*       ho = h_out + (size_t)img * NN * H;
    int nb = r0 * GRID_D;

    // ---- stage weights transposed (bf16) ----
    for (int idx = tid; idx < H * H; idx += 512) {
        int k = idx >> 6, j = idx & 63;
        wt[(size_t)j * LDK + k]        = (__bf16)Ws[idx];
        wt[(size_t)(64 + j) * LDK + k] = (__bf16)Wn[idx];
    }

    // ---- stage h tile + halo rows (zero-filled outside image) ----
    #pragma unroll
    for (int i = 0; i < 6; ++i) {
        int it = i * 512 + tid;              // 0..3071
        int c8 = it & 7, cc = (it >> 3) & 63, rr = it >> 9;   // rr 0..5
        int grow = r0 - 1 + rr;
        uint4 v = {0u, 0u, 0u, 0u};
        if (grow >= 0 && grow < GRID_D)
            v = *(const uint4*)&hb[(size_t)(grow * GRID_D + cc) * H + c8 * 8];
        *(uint4*)&st[(size_t)(rr * 66 + cc + 1) * LDK + c8 * 8] = v;
    }
    // zero col borders (col 0 and col 65)
    if (tid < 96) {
        int c8 = tid & 7, which = (tid >> 3) & 1, rr = tid >> 4;
        uint4 z = {0u, 0u, 0u, 0u};
        *(uint4*)&st[(size_t)(rr * 66 + (which ? 65 : 0)) * LDK + c8 * 8] = z;
    }
    __syncthreads();

    // ---- GEMM setup ----
    int wv = tid >> 6, ln = tid & 63;
    int lrow = ln & 15, kgrp = ln >> 4;
    int lr = wv >> 1;                   // wave's local grid row 0..3
    int cbase = (wv & 1) * 32;          // wave's column base (half row)
    int col0 = cbase + lrow;            // a0 column
    int col1 = cbase + 16 + lrow;       // a1 column
    int growc = r0 + lr;                // global grid row

    const __bf16* s0 = st + (size_t)((1 + lr) * 66 + 1 + col0) * LDK;
    const __bf16* s1 = st + (size_t)((1 + lr) * 66 + 1 + col1) * LDK;

    float deg0 = (float)((growc > 0) + (growc < 63) + (col0 > 0) + (col0 < 63));
    float deg1 = (float)((growc > 0) + (growc < 63) + (col1 > 0) + (col1 < 63));
    float inv0 = 1.0f / deg0, inv1 = 1.0f / deg1;

    f32x4 acc[2][4];
    #pragma unroll
    for (int nt = 0; nt < 2; ++nt)
        #pragma unroll
        for (int ft = 0; ft < 4; ++ft) acc[nt][ft] = (f32x4){0.f, 0.f, 0.f, 0.f};

    // ---- phase 1: self @ Ws (A-frags straight from tile) ----
    #pragma unroll
    for (int ks = 0; ks < 2; ++ks) {
        int k0 = ks * 32 + kgrp * 8;
        bf16x8 a0 = *(const bf16x8*)(s0 + k0);
        bf16x8 a1 = *(const bf16x8*)(s1 + k0);
        #pragma unroll
        for (int ft = 0; ft < 4; ++ft) {
            bf16x8 bfrag = *(const bf16x8*)&wt[(size_t)(ft * 16 + lrow) * LDK + k0];
            acc[0][ft] = __builtin_amdgcn_mfma_f32_16x16x32_bf16(a0, bfrag, acc[0][ft], 0, 0, 0);
            acc[1][ft] = __builtin_amdgcn_mfma_f32_16x16x32_bf16(a1, bfrag, acc[1][ft], 0, 0, 0);
        }
    }

    // ---- phase 2: agg @ Wn (A-frags built on the fly) ----
    #pragma unroll
    for (int ks = 0; ks < 2; ++ks) {
        int k0 = ks * 32 + kgrp * 8;
        bf16x8 g0 = agg_frag(s0 - LDK + k0, s0 + LDK + k0,
                             s0 - ST_ROW_STRIDE + k0, s0 + ST_ROW_STRIDE + k0, inv0);
        bf16x8 g1 = agg_frag(s1 - LDK + k0, s1 + LDK + k0,
                             s1 - ST_ROW_STRIDE + k0, s1 + ST_ROW_STRIDE + k0, inv1);
        #pragma unroll
        for (int ft = 0; ft < 4; ++ft) {
            bf16x8 bfrag = *(const bf16x8*)&wt[(size_t)(64 + ft * 16 + lrow) * LDK + k0];
            acc[0][ft] = __builtin_amdgcn_mfma_f32_16x16x32_bf16(g0, bfrag, acc[0][ft], 0, 0, 0);
            acc[1][ft] = __builtin_amdgcn_mfma_f32_16x16x32_bf16(g1, bfrag, acc[1][ft], 0, 0, 0);
        }
    }

    // ---- epilogue: +bias, LN over 64 feats, residual (from LDS) + ReLU ----
    float cbv[4], lgv[4], lbv[4], whv[4];
    #pragma unroll
    for (int ft = 0; ft < 4; ++ft) {
        int j = ft * 16 + lrow;
        cbv[ft] = cb[j]; lgv[ft] = lg[j]; lbv[ft] = lb[j];
        if (LAST) whv[ft] = w_head[j];
    }
    float bh = LAST ? b_head[0] : 0.f;

    #pragma unroll
    for (int nt = 0; nt < 2; ++nt) {
        #pragma unroll
        for (int t = 0; t < 4; ++t) {
            int nl   = wv * 32 + nt * 16 + 4 * kgrp + t;   // block-local node
            int colc = cbase + nt * 16 + 4 * kgrp + t;     // its grid column
            float v[4], s1v = 0.f, s2v = 0.f;
            #pragma unroll
            for (int ft = 0; ft < 4; ++ft) {
                float xv = acc[nt][ft][t] + cbv[ft];
                v[ft] = xv; s1v += xv; s2v += xv * xv;
            }
            #pragma unroll
            for (int m = 1; m < 16; m <<= 1) {
                s1v += __shfl_xor(s1v, m);
                s2v += __shfl_xor(s2v, m);
            }
            float mu   = s1v * (1.0f / H);
            float var  = s2v * (1.0f / H) - mu * mu;
            float rstd = rsqrtf(var + LN_EPS);
            const __bf16* res = st + (size_t)((1 + lr) * 66 + 1 + colc) * LDK;
            if (LAST) {
                float part = 0.f;
                #pragma unroll
                for (int ft = 0; ft < 4; ++ft) {
                    int j = ft * 16 + lrow;
                    float sv = (float)res[j];
                    float o  = sv + fmaxf((v[ft] - mu) * rstd * lgv[ft] + lbv[ft], 0.f);
                    part += o * whv[ft];
                }
                #pragma unroll
                for (int m = 1; m < 16; m <<= 1) part += __shfl_xor(part, m);
                if (lrow == 0) logits[(size_t)img * NN + nb + nl] = part + bh;
            } else {
                #pragma unroll
                for (int ft = 0; ft < 4; ++ft) {
                    int j = ft * 16 + lrow;
                    float sv = (float)res[j];
                    float o  = sv + fmaxf((v[ft] - mu) * rstd * lgv[ft] + lbv[ft], 0.f);
                    ho[(size_t)(nb + nl) * H + j] = (__bf16)o;
                }
            }
        }
    }
}

// ---------------------------------------------------------------------------
extern "C" void kernel_launch(void* const* d_in, const int* in_sizes, int n_in,
                              void* d_out, int out_size, void* d_ws, size_t ws_size,
                              hipStream_t stream) {
    const float* x      = (const float*)d_in[0];
    // d_in[1] edge_index: fixed grid 4-neighborhood -> computed as stencil, unused
    const float* w_in   = (const float*)d_in[2];
    const float* b_in   = (const float*)d_in[3];
    const float* w_self = (const float*)d_in[4];
    const float* w_neigh= (const float*)d_in[5];
    const float* conv_b = (const float*)d_in[6];
    const float* ln_g   = (const float*)d_in[7];
    const float* ln_b   = (const float*)d_in[8];
    const float* w_head = (const float*)d_in[9];
    const float* b_head = (const float*)d_in[10];
    float* out = (float*)d_out;

    __bf16* h_a = (__bf16*)d_ws;
    __bf16* h_b = h_a + (size_t)B_SZ * NN * H;

    // allow >64KB dynamic LDS (75,456 B per block)
    (void)hipFuncSetAttribute(reinterpret_cast<const void*>(&k_layer<false>),
                              hipFuncAttributeMaxDynamicSharedMemorySize, SMEM_BYTES);
    (void)hipFuncSetAttribute(reinterpret_cast<const void*>(&k_layer<true>),
                              hipFuncAttributeMaxDynamicSharedMemorySize, SMEM_BYTES);

    k_inproj<<<B_SZ * GRID_D, 256, 0, stream>>>(x, w_in, b_in, h_a);
    k_layer<false><<<B_SZ * 16, 512, SMEM_BYTES, stream>>>(
        h_a, h_b, out, w_self, w_neigh, conv_b, ln_g, ln_b, w_head, b_head);
    k_layer<false><<<B_SZ * 16, 512, SMEM_BYTES, stream>>>(
        h_b, h_a, out, w_self + H * H, w_neigh + H * H,
        conv_b + H, ln_g + H, ln_b + H, w_head, b_head);
    k_layer<true><<<B_SZ * 16, 512, SMEM_BYTES, stream>>>(
        h_a, h_b, out, w_self + 2 * H * H, w_neigh + 2 * H * H,
        conv_b + 2 * H, ln_g + 2 * H, ln_b + 2 * H, w_head, b_head);
}